// Round 1
// 767.415 us; speedup vs baseline: 1.1976x; 1.1976x over previous
//
#include <hip/hip_runtime.h>
#include <hip/hip_bf16.h>
#include <math.h>

// MistralAttention_offloading. R6 (perf): attn_kernel rework.
// - Causal bounds on gattn/QK^T/PV/softmax (avg ~2x less key work).
// - Selection skipped entirely when q0+8 <= 256 (all valid keys rank < 256).
// - Top-256 selection: bit-plane radix select (32x32 bit transpose once,
//   then and+popc per bit) with DPP quad_perm/row_ror reduce + early exit.
//   Replaces 32x(32 cmp + 5 chained ds_swizzle). Identical threshold and
//   stable-tie semantics -> bit-identical selection.
// - sBuf f32 XOR swizzle (col-block keyed) kills the 32-way ds_read_b128
//   conflict; P overlay bf16 swizzle (row keyed) kills PV's 16-way.
// - RoPE: inv_freq (double pow) and cos/sin hoisted to table kernels
//   (identical expressions -> bit-identical values).
// GEMMs unchanged from R5.

typedef __hip_bfloat16 bf16;
typedef unsigned short ushort_t;
typedef __attribute__((ext_vector_type(8))) short short8;
typedef __attribute__((ext_vector_type(4))) float f32x4;

#define QL   1024
#define DM   4096
#define NH   32
#define NKV  8
#define GRP  4      // NH/NKV
#define HD   128
#define OUTL 16     // HD/GROUP_FACTOR
#define HC   256    // HEAVY_CONST
#define MNEG (-1.0e30f)

// order-preserving float -> uint map (descending float order == descending uint)
__device__ __forceinline__ unsigned mapf(float f) {
  unsigned u = __float_as_uint(f);
  return (u & 0x80000000u) ? ~u : (u | 0x80000000u);
}

// round-to-nearest-even fp32 -> bf16 bits
__device__ __forceinline__ unsigned short f2bf(float x) {
  unsigned u = __float_as_uint(x);
  unsigned r = (u + 0x7FFFu + ((u >> 16) & 1u)) >> 16;
  return (unsigned short)r;
}
__device__ __forceinline__ float bf2f(unsigned short h) {
  return __uint_as_float(((unsigned)h) << 16);
}

__device__ __forceinline__ short8 cvt8(const float* p) {
  f32x4 a = *(const f32x4*)p;
  f32x4 b = *(const f32x4*)(p + 4);
  short8 r;
#pragma unroll
  for (int i = 0; i < 4; i++) r[i] = (short)f2bf(a[i]);
#pragma unroll
  for (int i = 0; i < 4; i++) r[4 + i] = (short)f2bf(b[i]);
  return r;
}

// split fp32x8 -> bf16 hi + bf16 residual lo
__device__ __forceinline__ void split8(const float* p, short8& h, short8& l) {
  f32x4 a = *(const f32x4*)p;
  f32x4 b = *(const f32x4*)(p + 4);
#pragma unroll
  for (int i = 0; i < 4; i++) {
    unsigned short hh = f2bf(a[i]);
    h[i] = (short)hh;
    l[i] = (short)f2bf(a[i] - bf2f(hh));
  }
#pragma unroll
  for (int i = 0; i < 4; i++) {
    unsigned short hh = f2bf(b[i]);
    h[4 + i] = (short)hh;
    l[4 + i] = (short)f2bf(b[i] - bf2f(hh));
  }
}

// swizzled sB index for the GEMM kernels (unchanged from R5)
__device__ __forceinline__ int bswz(int n, int k) {
  return n * 32 + (k ^ (((n >> 3) & 3) * 8));
}

// sBuf f32 column swizzle: keyed on col>>5 (the reader lane), xor on bits
// [2:4] -> preserves aligned f32x4 runs, spreads 32-way conflict to ~4-way.
__device__ __forceinline__ int s4(int col) {
  return col ^ (((col >> 5) & 7) << 2);
}

// 32-lane integer sum reduce via DPP (quad xor1, xor2, row_ror 4, 8) + one
// ds_swizzle xor16. ~15cy dependency chain vs ~150cy for 5 chained swizzles.
__device__ __forceinline__ int dppReduce32(int v) {
  v += __builtin_amdgcn_update_dpp(0, v, 0xB1, 0xF, 0xF, true);   // quad_perm [1,0,3,2]
  v += __builtin_amdgcn_update_dpp(0, v, 0x4E, 0xF, 0xF, true);   // quad_perm [2,3,0,1]
  v += __builtin_amdgcn_update_dpp(0, v, 0x124, 0xF, 0xF, true);  // row_ror:4
  v += __builtin_amdgcn_update_dpp(0, v, 0x128, 0xF, 0xF, true);  // row_ror:8
  v += __builtin_amdgcn_ds_swizzle(v, 0x401F);                    // xor16 within 32
  return v;
}

// ---------------------------------------------------------------------------
// Transpose bf16: src K x N (row-major) -> dst N x K. 64x64 tiles, XOR swizzle.
__global__ __launch_bounds__(256)
void transpose_bf16_kernel(const bf16* __restrict__ src, bf16* __restrict__ dst,
                           int K, int N, long long srcBS, long long dstBS) {
  __shared__ alignas(16) unsigned short tile[64][64];
  const bf16* s = src + (size_t)blockIdx.z * srcBS;
  bf16* d = dst + (size_t)blockIdx.z * dstBS;
  const int k0 = blockIdx.y * 64, n0 = blockIdx.x * 64;
  const int t = threadIdx.x;
  {
    const int r = t >> 3;
    const int c8 = (t & 7) * 8;
    const int sw0 = ((r >> 3) & 7) * 8;
    const int sw1 = (((r + 32) >> 3) & 7) * 8;
    *(short8*)&tile[r][c8 ^ sw0] =
        *(const short8*)&s[(size_t)(k0 + r) * N + n0 + c8];
    *(short8*)&tile[r + 32][c8 ^ sw1] =
        *(const short8*)&s[(size_t)(k0 + r + 32) * N + n0 + c8];
  }
  __syncthreads();
  {
    const int kc8 = t & 7;
    const int nr = t >> 3;
    short8 v0, v1;
#pragma unroll
    for (int j = 0; j < 8; j++) {
      const int rowj = kc8 * 8 + j;
      const int swj = ((rowj >> 3) & 7) * 8;
      v0[j] = (short)tile[rowj][nr ^ swj];
      v1[j] = (short)tile[rowj][(nr + 32) ^ swj];
    }
    *(short8*)&d[(size_t)(n0 + nr) * K + k0 + kc8 * 8] = v0;
    *(short8*)&d[(size_t)(n0 + nr + 32) * K + k0 + kc8 * 8] = v1;
  }
}

// ---------------------------------------------------------------------------
// Fused QKV projection (unchanged from R5)
__global__ __launch_bounds__(256)
void gemm_qkv_kernel(const void* __restrict__ hsv, const void* __restrict__ Wqv,
                     const void* __restrict__ Wkv, const void* __restrict__ Wvv,
                     float* __restrict__ C, const ushort_t* __restrict__ msk) {
  const bool ibf = (msk[1] != 0);
  const int n0 = blockIdx.x * 128;
  const int m0 = blockIdx.y * 64;
  const void* Bv;
  int Nb, cb;
  bool wantSplit;
  if (n0 < 4096)      { Bv = Wqv; Nb = 4096; cb = n0;        wantSplit = true; }
  else if (n0 < 5120) { Bv = Wkv; Nb = 1024; cb = n0 - 4096; wantSplit = true; }
  else                { Bv = Wvv; Nb = 1024; cb = n0 - 5120; wantSplit = false; }
  const bool doSplit = wantSplit && !ibf;

  __shared__ alignas(16) bf16 sAh[64 * 32];
  __shared__ alignas(16) bf16 sAl[64 * 32];
  __shared__ alignas(16) bf16 sBh[128 * 32];   // swizzled [n][k]
  __shared__ alignas(16) bf16 sBl[128 * 32];

  const int t = threadIdx.x, lane = t & 63, wave = t >> 6;
  const int wm = (wave >> 1) * 32, wn = (wave & 1) * 64;
  const int mrow = lane & 15, kq = (lane >> 4) * 8;
  const int r0 = t >> 2, o0 = (t & 3) * 8;    // A staging: 64 rows x 32 k
  const int bk2 = (t >> 4) * 2;               // B staging: k pair
  const int bn8 = (t & 15) * 8;               // B staging: n group
  f32x4 acc[2][4];
#pragma unroll
  for (int i = 0; i < 2; i++)
#pragma unroll
    for (int j = 0; j < 4; j++) acc[i][j] = (f32x4){0.f, 0.f, 0.f, 0.f};

  for (int kk = 0; kk < DM; kk += 32) {
    short8 ah, al, bh0, bl0, bh1, bl1;
    if (ibf) {
      const bf16* A = (const bf16*)hsv;
      const bf16* B = (const bf16*)Bv;
      ah = *(const short8*)&A[(size_t)(m0 + r0) * DM + kk + o0];
      bh0 = *(const short8*)&B[(size_t)(kk + bk2) * Nb + cb + bn8];
      bh1 = *(const short8*)&B[(size_t)(kk + bk2 + 1) * Nb + cb + bn8];
    } else {
      const float* A = (const float*)hsv;
      const float* B = (const float*)Bv;
      split8(&A[(size_t)(m0 + r0) * DM + kk + o0], ah, al);
      if (doSplit) {
        split8(&B[(size_t)(kk + bk2) * Nb + cb + bn8], bh0, bl0);
        split8(&B[(size_t)(kk + bk2 + 1) * Nb + cb + bn8], bh1, bl1);
      } else {
        bh0 = cvt8(&B[(size_t)(kk + bk2) * Nb + cb + bn8]);
        bh1 = cvt8(&B[(size_t)(kk + bk2 + 1) * Nb + cb + bn8]);
      }
    }
    __syncthreads();
    *(short8*)&sAh[r0 * 32 + o0] = ah;
    if (doSplit) *(short8*)&sAl[r0 * 32 + o0] = al;
#pragma unroll
    for (int i = 0; i < 8; i++) {
      unsigned pv = (unsigned)(unsigned short)bh0[i] |
                    ((unsigned)(unsigned short)bh1[i] << 16);
      *(unsigned*)&sBh[bswz(bn8 + i, bk2)] = pv;
    }
    if (doSplit) {
#pragma unroll
      for (int i = 0; i < 8; i++) {
        unsigned pv = (unsigned)(unsigned short)bl0[i] |
                      ((unsigned)(unsigned short)bl1[i] << 16);
        *(unsigned*)&sBl[bswz(bn8 + i, bk2)] = pv;
      }
    }
    __syncthreads();
    short8 afh[2], bfh[4];
#pragma unroll
    for (int i = 0; i < 2; i++)
      afh[i] = *(const short8*)&sAh[(wm + i * 16 + mrow) * 32 + kq];
#pragma unroll
    for (int j = 0; j < 4; j++)
      bfh[j] = *(const short8*)&sBh[bswz(wn + j * 16 + mrow, kq)];
#pragma unroll
    for (int i = 0; i < 2; i++)
#pragma unroll
      for (int j = 0; j < 4; j++)
        acc[i][j] = __builtin_amdgcn_mfma_f32_16x16x32_bf16(afh[i], bfh[j], acc[i][j], 0, 0, 0);
    if (doSplit) {
      short8 afl[2], bfl[4];
#pragma unroll
      for (int i = 0; i < 2; i++)
        afl[i] = *(const short8*)&sAl[(wm + i * 16 + mrow) * 32 + kq];
#pragma unroll
      for (int j = 0; j < 4; j++)
        bfl[j] = *(const short8*)&sBl[bswz(wn + j * 16 + mrow, kq)];
#pragma unroll
      for (int i = 0; i < 2; i++)
#pragma unroll
        for (int j = 0; j < 4; j++) {
          acc[i][j] = __builtin_amdgcn_mfma_f32_16x16x32_bf16(afh[i], bfl[j], acc[i][j], 0, 0, 0);
          acc[i][j] = __builtin_amdgcn_mfma_f32_16x16x32_bf16(afl[i], bfh[j], acc[i][j], 0, 0, 0);
        }
    }
  }
  const int rq = (lane >> 4) * 4, cn = lane & 15;
#pragma unroll
  for (int i = 0; i < 2; i++)
#pragma unroll
    for (int r = 0; r < 4; r++) {
      const size_t rowi = (size_t)(m0 + wm + i * 16 + rq + r);
#pragma unroll
      for (int j = 0; j < 4; j++)
        C[rowi * 6144 + (n0 + wn + j * 16 + cn)] = acc[i][j][r];
    }
}

// ---------------------------------------------------------------------------
// Wo GEMM (unchanged from R5)
__global__ __launch_bounds__(256)
void gemm_wo_kernel(const bf16* __restrict__ A, const void* __restrict__ Bv,
                    void* __restrict__ Cv, const ushort_t* __restrict__ msk) {
  const bool ibf = (msk[1] != 0);
  __shared__ alignas(16) bf16 sA[64 * 32];
  __shared__ alignas(16) bf16 sB[128 * 32];   // swizzled [n][k]
  const int n0 = blockIdx.x * 128;
  const int m0 = blockIdx.y * 64;
  const int t = threadIdx.x, lane = t & 63, wave = t >> 6;
  const int wm = (wave >> 1) * 32, wn = (wave & 1) * 64;
  const int mrow = lane & 15, kq = (lane >> 4) * 8;
  const int r0 = t >> 2, o0 = (t & 3) * 8;
  const int bk2 = (t >> 4) * 2;
  const int bn8 = (t & 15) * 8;
  f32x4 acc[2][4];
#pragma unroll
  for (int i = 0; i < 2; i++)
#pragma unroll
    for (int j = 0; j < 4; j++) acc[i][j] = (f32x4){0.f, 0.f, 0.f, 0.f};

  for (int kk = 0; kk < DM; kk += 32) {
    short8 av = *(const short8*)&A[(size_t)(m0 + r0) * DM + kk + o0];
    short8 bv0, bv1;
    if (ibf) {
      const bf16* B = (const bf16*)Bv;
      bv0 = *(const short8*)&B[(size_t)(kk + bk2) * DM + n0 + bn8];
      bv1 = *(const short8*)&B[(size_t)(kk + bk2 + 1) * DM + n0 + bn8];
    } else {
      const float* B = (const float*)Bv;
      bv0 = cvt8(&B[(size_t)(kk + bk2) * DM + n0 + bn8]);
      bv1 = cvt8(&B[(size_t)(kk + bk2 + 1) * DM + n0 + bn8]);
    }
    __syncthreads();
    *(short8*)&sA[r0 * 32 + o0] = av;
#pragma unroll
    for (int i = 0; i < 8; i++) {
      unsigned pv = (unsigned)(unsigned short)bv0[i] |
                    ((unsigned)(unsigned short)bv1[i] << 16);
      *(unsigned*)&sB[bswz(bn8 + i, bk2)] = pv;
    }
    __syncthreads();
    short8 af[2], bfr[4];
#pragma unroll
    for (int i = 0; i < 2; i++)
      af[i] = *(const short8*)&sA[(wm + i * 16 + mrow) * 32 + kq];
#pragma unroll
    for (int j = 0; j < 4; j++)
      bfr[j] = *(const short8*)&sB[bswz(wn + j * 16 + mrow, kq)];
#pragma unroll
    for (int i = 0; i < 2; i++)
#pragma unroll
      for (int j = 0; j < 4; j++)
        acc[i][j] = __builtin_amdgcn_mfma_f32_16x16x32_bf16(af[i], bfr[j], acc[i][j], 0, 0, 0);
  }
  const int rq = (lane >> 4) * 4, cn = lane & 15;
#pragma unroll
  for (int i = 0; i < 2; i++)
#pragma unroll
    for (int r = 0; r < 4; r++) {
      const size_t rowi = (size_t)(m0 + wm + i * 16 + rq + r);
#pragma unroll
      for (int j = 0; j < 4; j++) {
        const size_t idx = rowi * DM + (n0 + wn + j * 16 + cn);
        if (ibf)
          ((bf16*)Cv)[idx] = __float2bfloat16(acc[i][j][r]);
        else
          ((float*)Cv)[idx] = acc[i][j][r];
      }
    }
}

// ---------------------------------------------------------------------------
// RoPE tables. tab: inv_freq via double pow (bit-identical to the per-thread
// expression R5 used). cs/sn: cos/sin per (pos, d) computed once instead of
// once per (pos, head, d).
__global__ __launch_bounds__(64)
void rope_tab_kernel(float* __restrict__ tab) {
  const int i = threadIdx.x;
  tab[i] = (float)(1.0 / pow(10000.0, (double)i * (1.0 / 64.0)));
}

__global__ __launch_bounds__(128)
void rope_cs_kernel(const float* __restrict__ tab, float* __restrict__ cs,
                    float* __restrict__ sn) {
  const int pos = blockIdx.x, d = threadIdx.x;
  const float inv = tab[d & 63];
  const float ang = (float)pos * inv;
  cs[pos * HD + d] = cosf(ang);
  sn[pos * HD + d] = sinf(ang);
}

// RoPE for q + gq quantization. block=(128 threads)=one (h,pos).
__global__ __launch_bounds__(128)
void rope_q_gq_kernel(const float* __restrict__ qkv, const int* __restrict__ sc,
                      bf16* __restrict__ qr, float* __restrict__ gq,
                      const float* __restrict__ cs, const float* __restrict__ sn) {
  const int pos = blockIdx.x, h = blockIdx.y, d = threadIdx.x;
  __shared__ float sv[HD], sr[HD];
  __shared__ float smn, smx;
  float v = qkv[(size_t)pos * 6144 + h * HD + d];
  sv[d] = v;
  __syncthreads();
  const float c = cs[pos * HD + d], s = sn[pos * HD + d];
  float rot = (d < 64) ? -sv[d + 64] : sv[d - 64];
  float r = v * c + rot * s;
  sr[d] = r;
  qr[((size_t)h * QL + pos) * HD + d] = __float2bfloat16(r);
  __syncthreads();
  if (d == 0) {
    float mn = 3.4e38f, mx = -3.4e38f;
    for (int j = 0; j < OUTL; j++) {
      float g = sr[sc[h * HD + j]];
      mn = fminf(mn, g);
      mx = fmaxf(mx, g);
    }
    smn = mn; smx = mx;
  }
  __syncthreads();
  if (d < OUTL) {
    float g = sr[sc[h * HD + d]];
    float rng = smx - smn;
    if (rng == 0.f) rng = 1.f;
    float scale = 15.0f / rng;
    float qv = rintf((g - smn) * scale);
    qv = fminf(fmaxf(qv, 0.f), 15.f);
    gq[((size_t)h * QL + pos) * OUTL + d] = qv / scale + smn;
  }
}

// RoPE for k + gk quantization (per query-head) + v row cast.
__global__ __launch_bounds__(128)
void rope_k_gk_kernel(const float* __restrict__ qkv, const int* __restrict__ sc,
                      bf16* __restrict__ kr, bf16* __restrict__ vrow,
                      float* __restrict__ gk,
                      const float* __restrict__ cs, const float* __restrict__ sn) {
  const int pos = blockIdx.x, kvh = blockIdx.y, d = threadIdx.x;
  __shared__ float sv[HD], sr[HD];
  __shared__ float smn[GRP], smx[GRP];
  float kv = qkv[(size_t)pos * 6144 + DM + kvh * HD + d];
  float vv = qkv[(size_t)pos * 6144 + DM + NKV * HD + kvh * HD + d];
  sv[d] = kv;
  __syncthreads();
  const float c = cs[pos * HD + d], s = sn[pos * HD + d];
  float rot = (d < 64) ? -sv[d + 64] : sv[d - 64];
  float r = kv * c + rot * s;
  sr[d] = r;
  kr[((size_t)kvh * QL + pos) * HD + d] = __float2bfloat16(r);
  vrow[((size_t)kvh * QL + pos) * HD + d] = __float2bfloat16(vv);
  __syncthreads();
  if (d < 64 && (d & 15) == 0) {
    const int g = d >> 4;
    const int h = kvh * GRP + g;
    float mn = 3.4e38f, mx = -3.4e38f;
    for (int j = 0; j < OUTL; j++) {
      float x = sr[sc[h * HD + j]];
      mn = fminf(mn, x);
      mx = fmaxf(mx, x);
    }
    smn[g] = mn; smx[g] = mx;
  }
  __syncthreads();
  if (d < 64) {
    const int g = d >> 4, j = d & 15;
    const int h = kvh * GRP + g;
    float x = sr[sc[h * HD + j]];
    float rng = smx[g] - smn[g];
    if (rng == 0.f) rng = 1.f;
    float scale = 15.0f / rng;
    float qv = rintf((x - smn[g]) * scale);
    qv = fminf(fmaxf(qv, 0.f), 15.f);
    gk[((size_t)h * QL + pos) * OUTL + j] = qv / scale + smn[g];
  }
}

// ---------------------------------------------------------------------------
// Fused attention: one block = (head h, 8 queries). 256 threads = 4 waves.
__global__ __launch_bounds__(256)
void attn_kernel(const bf16* __restrict__ qr, const bf16* __restrict__ kr,
                 const bf16* __restrict__ vT, const float* __restrict__ gq,
                 const float* __restrict__ gk, bf16* __restrict__ ao) {
  const int h = blockIdx.y;
  // heavy blocks (large q0) first for better tail packing
  const int q0 = ((int)gridDim.x - 1 - (int)blockIdx.x) * 8;
  const int kvh = h >> 2;
  const int t = threadIdx.x;
  const int lane = t & 63, wave = t >> 6;
  const int mrow = lane & 15, kq = (lane >> 4) * 8;
  const int row = t >> 5, j32 = t & 31;
  const int kmax = q0 + 8;              // keys [0, kmax) are ever valid
  const bool needSel = (kmax > HC);     // else all valid keys have rank < 256

  __shared__ alignas(16) bf16 sQ[16][HD];
  __shared__ float sGq[8][OUTL];
  __shared__ alignas(16) float sBuf[8][QL];
  __shared__ float sL[8];

  {
    const int r = t >> 4, c8 = (t & 15) * 8;
    short8 z = {0, 0, 0, 0, 0, 0, 0, 0};
    if (r < 8)
      *(short8*)&sQ[r][c8] = *(const short8*)&qr[((size_t)h * QL + q0 + r) * HD + c8];
    else
      *(short8*)&sQ[r][c8] = z;
    if (needSel && t < 128)
      sGq[t >> 4][t & 15] = gq[((size_t)h * QL + q0 + (t >> 4)) * OUTL + (t & 15)];
  }
  __syncthreads();

  unsigned sel = 0xFFFFFFFFu;
  if (needSel) {
    // ---- gattn (fp32, exact path for selection), causal-bounded
    for (int kk = t; kk < kmax; kk += 256) {
      const float* gkp = &gk[((size_t)h * QL + kk) * OUTL];
      float gv[OUTL];
#pragma unroll
      for (int j = 0; j < OUTL; j++) gv[j] = gkp[j];
      const int pk = s4(kk);
#pragma unroll
      for (int r = 0; r < 8; r++) {
        float s = 0.f;
#pragma unroll
        for (int j = 0; j < OUTL; j++) s += sGq[r][j] * gv[j];
        sBuf[r][pk] = (kk <= q0 + r) ? s * 0.25f : MNEG;
      }
    }
    __syncthreads();

    // ---- exact top-256 via bit-plane radix select (stable-tie semantics)
    {
      const int base = j32 * 32;
      const int cz = j32 & 7;
      unsigned uv[32];
#pragma unroll
      for (int g = 0; g < 8; g++) {
        f32x4 v = *(const f32x4*)&sBuf[row][base + ((g ^ cz) << 2)];
#pragma unroll
        for (int m = 0; m < 4; m++) {
          const int kk = g * 4 + m;
          uv[kk] = (base + kk < kmax) ? mapf(v[m]) : 0u;
        }
      }
      // in-place 32x32 bit transpose (anti-diagonal convention):
      // after: uv[p] bit (31-kk) == original uv[kk] bit (31-p)
#define TST(J, M)                                                     \
  _Pragma("unroll") for (int k2 = 0; k2 < 32; k2++) if ((k2 & (J)) == 0) { \
    unsigned tt = (uv[k2] ^ (uv[k2 + (J)] >> (J))) & (M);             \
    uv[k2] ^= tt;                                                     \
    uv[k2 + (J)] ^= (tt << (J));                                      \
  }
      TST(16, 0x0000FFFFu)
      TST(8, 0x00FF00FFu)
      TST(4, 0x0F0F0F0Fu)
      TST(2, 0x33333333u)
      TST(1, 0x55555555u)
#undef TST
      // MSB-first radix: plane p corresponds to value bit (31-p); masks are
      // in reversed-bit space (bit 31-kk <-> element kk), fixed by __brev.
      unsigned act = 0xFFFFFFFFu, gtm = 0u;
      int greater = 0, act_tot = QL;
      bool done = false;
#pragma unroll
      for (int p = 0; p < 32; p++) {
        if (__all(done)) break;
        if (!done) {
          const unsigned ones = act & uv[p];
          const int c = dppReduce32(__popc(ones));
          if (greater + c >= HC) {
            act = ones;
            act_tot = c;
          } else {
            greater += c;
            gtm |= ones;
            act ^= ones;
            act_tot -= c;
          }
          if (greater + act_tot == HC) {
            sel = __brev(gtm | act);
            done = true;
          }
        }
      }
      if (!done) {
        const unsigned gtmN = __brev(gtm), eqmN = __brev(act);
        const int needEq = HC - greater;
        const int eqc = __popc(eqmN);
        int pre = eqc;
#pragma unroll
        for (int dlt = 1; dlt < 32; dlt <<= 1) {
          int o = __shfl_up(pre, dlt, 32);
          if (j32 >= dlt) pre += o;
        }
        pre -= eqc;
        int take = needEq - pre;
        unsigned mm = eqmN;
        sel = gtmN;
        for (int i = 0; i < take && mm != 0u; i++) {
          unsigned b = mm & (0u - mm);
          sel |= b;
          mm ^= b;
        }
      }
    }
    __syncthreads();   // selection reads of sBuf done before QK overwrites
  }

  // ---- QK^T via MFMA, causal-bounded tiles
  {
    short8 aq[4];
#pragma unroll
    for (int kb = 0; kb < 4; kb++)
      aq[kb] = *(const short8*)&sQ[mrow][kb * 32 + kq];
    const bf16* krh = &kr[(size_t)kvh * QL * HD];
    const int ntmax = (kmax + 15) >> 4;
    for (int nt = wave; nt < ntmax; nt += 4) {
      const int kb0 = nt * 16;
      f32x4 acc = {0.f, 0.f, 0.f, 0.f};
#pragma unroll
      for (int kb = 0; kb < 4; kb++) {
        short8 bfr = *(const short8*)&krh[(size_t)(kb0 + mrow) * HD + kb * 32 + kq];
        acc = __builtin_amdgcn_mfma_f32_16x16x32_bf16(aq[kb], bfr, acc, 0, 0, 0);
      }
      const int key = kb0 + mrow;
      const int pk = s4(key);
#pragma unroll
      for (int r = 0; r < 4; r++) {
        const int m = (lane >> 4) * 4 + r;
        if (m < 8) {
          float v = acc[r] * 0.08838834764831845f;  // 1/sqrt(128)
          sBuf[m][pk] = (key <= q0 + m) ? v : MNEG;
        }
      }
    }
  }
  __syncthreads();

  const int kbmax = (kmax + 31) >> 5;   // PV tiles / P-overlay coverage

  // ---- masked softmax; write p as bf16 overlay at sBuf base
  {
    const int base = j32 * 32;
    const int cz = j32 & 7;
    const int rbound = q0 + row;        // keys <= rbound are valid this row
    float av[32];
#pragma unroll
    for (int g = 0; g < 8; g++) {
      f32x4 v = *(const f32x4*)&sBuf[row][base + ((g ^ cz) << 2)];
#pragma unroll
      for (int m = 0; m < 4; m++) av[g * 4 + m] = v[m];
    }
    float mx = MNEG;
#pragma unroll
    for (int kk = 0; kk < 32; kk++)
      if (((sel >> kk) & 1u) && (base + kk <= rbound)) mx = fmaxf(mx, av[kk]);
    mx = fmaxf(mx, __shfl_xor(mx, 1, 32));
    mx = fmaxf(mx, __shfl_xor(mx, 2, 32));
    mx = fmaxf(mx, __shfl_xor(mx, 4, 32));
    mx = fmaxf(mx, __shfl_xor(mx, 8, 32));
    mx = fmaxf(mx, __shfl_xor(mx, 16, 32));
    float ls = 0.f;
#pragma unroll
    for (int kk = 0; kk < 32; kk++) {
      float p = 0.f;
      if (((sel >> kk) & 1u) && (base + kk <= rbound)) {
        float e = av[kk] - mx;
        p = (e < -80.f) ? 0.f : expf(e);
        ls += p;
      }
      av[kk] = p;
    }
    ls += __shfl_xor(ls, 1, 32);
    ls += __shfl_xor(ls, 2, 32);
    ls += __shfl_xor(ls, 4, 32);
    ls += __shfl_xor(ls, 8, 32);
    ls += __shfl_xor(ls, 16, 32);
    if (j32 == 0) sL[row] = ls;
    __syncthreads();
    bf16* P = (bf16*)&sBuf[0][0];
    if (j32 < kbmax) {
      const int rk = row & 3;           // row-keyed bf16 swizzle (PV reads)
#pragma unroll
      for (int g = 0; g < 4; g++) {
        short8 pv8;
#pragma unroll
        for (int m = 0; m < 8; m++) pv8[m] = (short)f2bf(av[g * 8 + m]);
        *(short8*)&P[(size_t)row * QL + base + ((g ^ rk) << 3)] = pv8;
      }
    }
    // zero rows 8..15 of P over the PV-covered range (zeros are
    // swizzle-invariant: swizzle permutes within 32-col blocks)
    {
      const int zr = 8 + row;
      if (j32 < kbmax) {
        short8 z = {0, 0, 0, 0, 0, 0, 0, 0};
#pragma unroll
        for (int i = 0; i < 4; i++)
          *(short8*)&P[(size_t)zr * QL + j32 * 32 + i * 8] = z;
      }
    }
  }
  __syncthreads();

  // ---- PV via MFMA, causal-bounded tiles (unselected p == 0)
  {
    const bf16* Pb = (const bf16*)&sBuf[0][0];
    const bf16* vTh = &vT[(size_t)kvh * HD * QL];
    const int rk = mrow & 3;
    for (int dt = wave; dt < 8; dt += 4) {
      const int d0 = dt * 16;
      f32x4 acc = {0.f, 0.f, 0.f, 0.f};
      for (int kb = 0; kb < kbmax; kb++) {
        short8 af = *(const short8*)&Pb[(size_t)mrow * QL + kb * 32 + (kq ^ (rk << 3))];
        short8 bfr = *(const short8*)&vTh[(size_t)(d0 + mrow) * QL + kb * 32 + kq];
        acc = __builtin_amdgcn_mfma_f32_16x16x32_bf16(af, bfr, acc, 0, 0, 0);
      }
#pragma unroll
      for (int r = 0; r < 4; r++) {
        const int m = (lane >> 4) * 4 + r;
        if (m < 8) {
          float outv = acc[r] / sL[m];
          ao[(size_t)(q0 + m) * DM + h * HD + d0 + mrow] = __float2bfloat16(outv);
        }
      }
    }
  }
}

// ---------------------------------------------------------------------------
extern "C" void kernel_launch(void* const* d_in, const int* in_sizes, int n_in,
                              void* d_out, int out_size, void* d_ws, size_t ws_size,
                              hipStream_t stream) {
  (void)in_sizes; (void)n_in; (void)out_size; (void)ws_size;
  const void* hs = d_in[0];
  const ushort_t* msk = (const ushort_t*)d_in[1];  // dtype discriminator
  const void* Wq = d_in[3];
  const void* Wk = d_in[4];
  const void* Wv = d_in[5];
  const void* Wo = d_in[6];
  const int* sc = (const int*)d_in[7];

  char* ws = (char*)d_ws;
  size_t off = 0;
  auto alloc = [&](size_t bytes) {
    char* p = ws + off;
    off += (bytes + 255) & ~(size_t)255;
    return p;
  };
  float* qkv = (float*)alloc((size_t)QL * 6144 * 4);   // 25.2 MB
  bf16* ao = (bf16*)qkv;                               // aliases dead qkv
  bf16* qr = (bf16*)alloc((size_t)NH * QL * HD * 2);
  bf16* kr = (bf16*)alloc((size_t)NKV * QL * HD * 2);
  bf16* vrow = (bf16*)alloc((size_t)NKV * QL * HD * 2);
  bf16* vT = (bf16*)alloc((size_t)NKV * HD * QL * 2);
  float* gq = (float*)alloc((size_t)NH * QL * OUTL * 4);
  float* gk = (float*)alloc((size_t)NH * QL * OUTL * 4);
  float* tab = (float*)alloc(64 * 4);
  float* cst = (float*)alloc((size_t)QL * HD * 4);
  float* snt = (float*)alloc((size_t)QL * HD * 4);
  // total ~43 MB

  // 0. RoPE tables (tiny)
  rope_tab_kernel<<<1, 64, 0, stream>>>(tab);
  rope_cs_kernel<<<dim3(QL), 128, 0, stream>>>(tab, cst, snt);

  // 1. fused QKV projection (768 blocks, 3/CU)
  gemm_qkv_kernel<<<dim3(48, 16), 256, 0, stream>>>(hs, Wq, Wk, Wv, qkv, msk);

  // 2. RoPE + quantized-label prep
  rope_q_gq_kernel<<<dim3(QL, NH), 128, 0, stream>>>(qkv, sc, qr, gq, cst, snt);
  rope_k_gk_kernel<<<dim3(QL, NKV), 128, 0, stream>>>(qkv, sc, kr, vrow, gk, cst, snt);
  transpose_bf16_kernel<<<dim3(2, 16, NKV), 256, 0, stream>>>(
      vrow, vT, QL, HD, (long long)(QL * HD), (long long)(HD * QL));

  // 3. fused attention (writes ao over dead qkv region)
  attn_kernel<<<dim3(QL / 8, NH), 256, 0, stream>>>(qr, kr, vT, gq, gk, ao);

  // 4. output projection (512 blocks, 2/CU; out dtype follows input dtype)
  gemm_wo_kernel<<<dim3(32, 16), 256, 0, stream>>>(ao, Wo, d_out, msk);
}

// Round 2
// 626.788 us; speedup vs baseline: 1.4662x; 1.2244x over previous
//
#include <hip/hip_runtime.h>
#include <hip/hip_bf16.h>
#include <math.h>

// MistralAttention_offloading. R7 (perf): GEMM conversion hoist + DMA staging.
// - Prepass kernels split/transpose/swizzle hs and W into bf16 hi/lo once
//   (same f2bf/split expressions -> bit-identical numerics).
// - gemm_qkv2/gemm_wo2: pure-bf16 operands, global_load_lds width-16 staging
//   (no VALU conversion, no LDS write scatter), ds_read_b128 fragments with
//   (row>>1)&3 chunk swizzle (2 lanes/bank -> conflict-free).
// - attn writes ao in the swizzled layout gemm_wo2 expects.
// - WoT transpose aliases dead WhT buffer (ws ~155 MB).
// attn/rope otherwise unchanged from R6.

typedef __hip_bfloat16 bf16;
typedef unsigned short ushort_t;
typedef __attribute__((ext_vector_type(8))) short short8;
typedef __attribute__((ext_vector_type(4))) float f32x4;
typedef __attribute__((ext_vector_type(4))) unsigned u32x4;

#define QL   1024
#define DM   4096
#define NH   32
#define NKV  8
#define GRP  4      // NH/NKV
#define HD   128
#define OUTL 16     // HD/GROUP_FACTOR
#define HC   256    // HEAVY_CONST
#define MNEG (-1.0e30f)

// order-preserving float -> uint map (descending float order == descending uint)
__device__ __forceinline__ unsigned mapf(float f) {
  unsigned u = __float_as_uint(f);
  return (u & 0x80000000u) ? ~u : (u | 0x80000000u);
}

// round-to-nearest-even fp32 -> bf16 bits
__device__ __forceinline__ unsigned short f2bf(float x) {
  unsigned u = __float_as_uint(x);
  unsigned r = (u + 0x7FFFu + ((u >> 16) & 1u)) >> 16;
  return (unsigned short)r;
}
__device__ __forceinline__ float bf2f(unsigned short h) {
  return __uint_as_float(((unsigned)h) << 16);
}

// split fp32x8 -> bf16 hi + bf16 residual lo
__device__ __forceinline__ void split8(const float* p, short8& h, short8& l) {
  f32x4 a = *(const f32x4*)p;
  f32x4 b = *(const f32x4*)(p + 4);
#pragma unroll
  for (int i = 0; i < 4; i++) {
    unsigned short hh = f2bf(a[i]);
    h[i] = (short)hh;
    l[i] = (short)f2bf(a[i] - bf2f(hh));
  }
#pragma unroll
  for (int i = 0; i < 4; i++) {
    unsigned short hh = f2bf(b[i]);
    h[4 + i] = (short)hh;
    l[4 + i] = (short)f2bf(b[i] - bf2f(hh));
  }
}

// fp32x8 -> packed (hi | lo<<16) u32 x8
__device__ __forceinline__ void splitp8(const float* p, unsigned* o) {
  f32x4 a = *(const f32x4*)p;
  f32x4 b = *(const f32x4*)(p + 4);
#pragma unroll
  for (int i = 0; i < 4; i++) {
    unsigned short hh = f2bf(a[i]);
    unsigned short ll = f2bf(a[i] - bf2f(hh));
    o[i] = (unsigned)hh | ((unsigned)ll << 16);
  }
#pragma unroll
  for (int i = 0; i < 4; i++) {
    unsigned short hh = f2bf(b[i]);
    unsigned short ll = f2bf(b[i] - bf2f(hh));
    o[4 + i] = (unsigned)hh | ((unsigned)ll << 16);
  }
}

// fragment LDS index: row r, k elem. 16B-chunk XOR keyed (r>>1)&3 ->
// fragment ds_read_b128 spreads 64 lanes over all 32 banks (2/bank, free).
__device__ __forceinline__ int aswz(int r, int k) {
  return r * 32 + (k ^ (((r >> 1) & 3) << 3));
}

// async global->LDS 16B (wave-uniform LDS base + lane*16)
__device__ __forceinline__ void gll16(const bf16* g, bf16* l) {
  __builtin_amdgcn_global_load_lds(
      (const __attribute__((address_space(1))) void*)g,
      (__attribute__((address_space(3))) void*)l, 16, 0, 0);
}

// sBuf f32 column swizzle (attn scores)
__device__ __forceinline__ int s4(int col) {
  return col ^ (((col >> 5) & 7) << 2);
}

// 32-lane integer sum reduce via DPP + one ds_swizzle xor16.
__device__ __forceinline__ int dppReduce32(int v) {
  v += __builtin_amdgcn_update_dpp(0, v, 0xB1, 0xF, 0xF, true);   // quad_perm [1,0,3,2]
  v += __builtin_amdgcn_update_dpp(0, v, 0x4E, 0xF, 0xF, true);   // quad_perm [2,3,0,1]
  v += __builtin_amdgcn_update_dpp(0, v, 0x124, 0xF, 0xF, true);  // row_ror:4
  v += __builtin_amdgcn_update_dpp(0, v, 0x128, 0xF, 0xF, true);  // row_ror:8
  v += __builtin_amdgcn_ds_swizzle(v, 0x401F);                    // xor16 within 32
  return v;
}

// ---------------------------------------------------------------------------
// Transpose bf16: src K x N (row-major) -> dst N x K. 64x64 tiles, XOR swizzle.
__global__ __launch_bounds__(256)
void transpose_bf16_kernel(const bf16* __restrict__ src, bf16* __restrict__ dst,
                           int K, int N, long long srcBS, long long dstBS) {
  __shared__ alignas(16) unsigned short tile[64][64];
  const bf16* s = src + (size_t)blockIdx.z * srcBS;
  bf16* d = dst + (size_t)blockIdx.z * dstBS;
  const int k0 = blockIdx.y * 64, n0 = blockIdx.x * 64;
  const int t = threadIdx.x;
  {
    const int r = t >> 3;
    const int c8 = (t & 7) * 8;
    const int sw0 = ((r >> 3) & 7) * 8;
    const int sw1 = (((r + 32) >> 3) & 7) * 8;
    *(short8*)&tile[r][c8 ^ sw0] =
        *(const short8*)&s[(size_t)(k0 + r) * N + n0 + c8];
    *(short8*)&tile[r + 32][c8 ^ sw1] =
        *(const short8*)&s[(size_t)(k0 + r + 32) * N + n0 + c8];
  }
  __syncthreads();
  {
    const int kc8 = t & 7;
    const int nr = t >> 3;
    short8 v0, v1;
#pragma unroll
    for (int j = 0; j < 8; j++) {
      const int rowj = kc8 * 8 + j;
      const int swj = ((rowj >> 3) & 7) * 8;
      v0[j] = (short)tile[rowj][nr ^ swj];
      v1[j] = (short)tile[rowj][(nr + 32) ^ swj];
    }
    *(short8*)&d[(size_t)(n0 + nr) * K + k0 + kc8 * 8] = v0;
    *(short8*)&d[(size_t)(n0 + nr + 32) * K + k0 + kc8 * 8] = v1;
  }
}

// ---------------------------------------------------------------------------
// Prepass: hs [1024][4096] -> Ah/Al bf16, chunk-swizzled. 2048 blocks.
__global__ __launch_bounds__(256)
void split_a_kernel(const void* __restrict__ hsv, bf16* __restrict__ Ah,
                    bf16* __restrict__ Al, const ushort_t* __restrict__ msk) {
  const bool ibf = (msk[1] != 0);
  const int gid = blockIdx.x * 256 + threadIdx.x;
  const int m = gid >> 9, c = gid & 511;         // 512 chunks of 8 per row
  const int cs = c ^ ((m >> 1) & 3);             // low-2 chunk XOR
  const size_t srci = (size_t)m * DM + (size_t)c * 8;
  const size_t dsti = (size_t)m * DM + (size_t)cs * 8;
  if (ibf) {
    *(short8*)&Ah[dsti] = *(const short8*)((const bf16*)hsv + srci);
  } else {
    short8 h, l;
    split8((const float*)hsv + srci, h, l);
    *(short8*)&Ah[dsti] = h;
    *(short8*)&Al[dsti] = l;
  }
}

// ---------------------------------------------------------------------------
// Prepass: W [K=4096][Nsrc] -> dh/dl [n_off+Nsrc][4096] bf16 transposed,
// chunk-swizzled. 64x64 tiles via packed (hi|lo<<16) u32 LDS.
__global__ __launch_bounds__(256)
void wsplitT_kernel(const void* __restrict__ src, int Nsrc,
                    bf16* __restrict__ dh, bf16* __restrict__ dl,
                    int n_off, int wantLo, const ushort_t* __restrict__ msk) {
  const bool ibf = (msk[1] != 0);
  __shared__ alignas(16) unsigned tile[64][64];
  const int n0 = blockIdx.x * 64;   // src col tile
  const int k0 = blockIdx.y * 64;   // src row tile
  const int t = threadIdx.x;
  {
    const int r = t >> 3, c8 = (t & 7) * 8;
    unsigned p0[8], p1[8];
    if (ibf) {
      const bf16* S = (const bf16*)src;
      short8 v0 = *(const short8*)&S[(size_t)(k0 + r) * Nsrc + n0 + c8];
      short8 v1 = *(const short8*)&S[(size_t)(k0 + r + 32) * Nsrc + n0 + c8];
#pragma unroll
      for (int i = 0; i < 8; i++) {
        p0[i] = (unsigned)(unsigned short)v0[i];
        p1[i] = (unsigned)(unsigned short)v1[i];
      }
    } else {
      const float* S = (const float*)src;
      splitp8(&S[(size_t)(k0 + r) * Nsrc + n0 + c8], p0);
      splitp8(&S[(size_t)(k0 + r + 32) * Nsrc + n0 + c8], p1);
    }
    const int sw0 = ((r >> 3) & 7) * 8;
    const int sw1 = (((r + 32) >> 3) & 7) * 8;
    *(u32x4*)&tile[r][c8 ^ sw0] = *(u32x4*)&p0[0];
    *(u32x4*)&tile[r][(c8 ^ sw0) + 4] = *(u32x4*)&p0[4];
    *(u32x4*)&tile[r + 32][c8 ^ sw1] = *(u32x4*)&p1[0];
    *(u32x4*)&tile[r + 32][(c8 ^ sw1) + 4] = *(u32x4*)&p1[4];
  }
  __syncthreads();
  {
    const int kc8 = t & 7, nr = t >> 3;   // nr 0..31
    short8 h0, l0, h1, l1;
#pragma unroll
    for (int j = 0; j < 8; j++) {
      const int rowj = kc8 * 8 + j;
      const int swj = ((rowj >> 3) & 7) * 8;
      unsigned g0 = tile[rowj][nr ^ swj];
      unsigned g1 = tile[rowj][(nr + 32) ^ swj];
      h0[j] = (short)(g0 & 0xFFFFu); l0[j] = (short)(g0 >> 16);
      h1[j] = (short)(g1 & 0xFFFFu); l1[j] = (short)(g1 >> 16);
    }
    const int na = n_off + n0 + nr, nb = na + 32;
    const int cha = (k0 >> 3) + (kc8 ^ ((na >> 1) & 3));
    const int chb = (k0 >> 3) + (kc8 ^ ((nb >> 1) & 3));
    *(short8*)&dh[(size_t)na * DM + ((size_t)cha << 3)] = h0;
    *(short8*)&dh[(size_t)nb * DM + ((size_t)chb << 3)] = h1;
    if (wantLo && !ibf) {
      *(short8*)&dl[(size_t)na * DM + ((size_t)cha << 3)] = l0;
      *(short8*)&dl[(size_t)nb * DM + ((size_t)chb << 3)] = l1;
    }
  }
}

// ---------------------------------------------------------------------------
// Fused QKV projection from pre-split operands. Tile 64x128, BK=32,
// grid (48,16) = 768 blocks. Staging = global_load_lds (DMA), zero VALU conv.
__global__ __launch_bounds__(256)
void gemm_qkv2_kernel(const bf16* __restrict__ Ah, const bf16* __restrict__ Al,
                      const bf16* __restrict__ WhT, const bf16* __restrict__ WlT,
                      float* __restrict__ C, const ushort_t* __restrict__ msk) {
  const bool ibf = (msk[1] != 0);
  const int n0 = blockIdx.x * 128;   // output col / WhT row
  const int m0 = blockIdx.y * 64;
  const bool doSplit = (n0 < 5120) && !ibf;   // Q,K regions: 3-pass

  __shared__ alignas(16) bf16 sAh[64 * 32];
  __shared__ alignas(16) bf16 sAl[64 * 32];
  __shared__ alignas(16) bf16 sBh[128 * 32];
  __shared__ alignas(16) bf16 sBl[128 * 32];

  const int t = threadIdx.x, lane = t & 63, wave = t >> 6;
  const int wm = (wave >> 1) * 32, wn = (wave & 1) * 64;
  const int mrow = lane & 15, kq = (lane >> 4) * 8;
  // staging: thread t -> row t>>2, chunk t&3 (16B), LDS linear = t*16B
  const size_t aoff = (size_t)(m0 + (t >> 2)) * DM + (size_t)(t & 3) * 8;
  const size_t boff0 = (size_t)(n0 + (t >> 2)) * DM + (size_t)(t & 3) * 8;
  const size_t boff1 = (size_t)(n0 + 64 + (t >> 2)) * DM + (size_t)(t & 3) * 8;
  bf16* lA_h = sAh + wave * 512;
  bf16* lA_l = sAl + wave * 512;
  bf16* lB0h = sBh + wave * 512;
  bf16* lB1h = sBh + 2048 + wave * 512;
  bf16* lB0l = sBl + wave * 512;
  bf16* lB1l = sBl + 2048 + wave * 512;

  f32x4 acc[2][4];
#pragma unroll
  for (int i = 0; i < 2; i++)
#pragma unroll
    for (int j = 0; j < 4; j++) acc[i][j] = (f32x4){0.f, 0.f, 0.f, 0.f};

  for (int kk = 0; kk < DM; kk += 32) {
    __syncthreads();   // prev-step fragment reads complete before overwrite
    gll16(Ah + aoff + kk, lA_h);
    gll16(WhT + boff0 + kk, lB0h);
    gll16(WhT + boff1 + kk, lB1h);
    if (doSplit) {
      gll16(Al + aoff + kk, lA_l);
      gll16(WlT + boff0 + kk, lB0l);
      gll16(WlT + boff1 + kk, lB1l);
    }
    __syncthreads();   // vmcnt(0) drain: staging visible
    short8 afh[2], bfh[4];
#pragma unroll
    for (int i = 0; i < 2; i++)
      afh[i] = *(const short8*)&sAh[aswz(wm + i * 16 + mrow, kq)];
#pragma unroll
    for (int j = 0; j < 4; j++)
      bfh[j] = *(const short8*)&sBh[aswz(wn + j * 16 + mrow, kq)];
#pragma unroll
    for (int i = 0; i < 2; i++)
#pragma unroll
      for (int j = 0; j < 4; j++)
        acc[i][j] = __builtin_amdgcn_mfma_f32_16x16x32_bf16(afh[i], bfh[j], acc[i][j], 0, 0, 0);
    if (doSplit) {
      short8 afl[2], bfl[4];
#pragma unroll
      for (int i = 0; i < 2; i++)
        afl[i] = *(const short8*)&sAl[aswz(wm + i * 16 + mrow, kq)];
#pragma unroll
      for (int j = 0; j < 4; j++)
        bfl[j] = *(const short8*)&sBl[aswz(wn + j * 16 + mrow, kq)];
#pragma unroll
      for (int i = 0; i < 2; i++)
#pragma unroll
        for (int j = 0; j < 4; j++) {
          acc[i][j] = __builtin_amdgcn_mfma_f32_16x16x32_bf16(afh[i], bfl[j], acc[i][j], 0, 0, 0);
          acc[i][j] = __builtin_amdgcn_mfma_f32_16x16x32_bf16(afl[i], bfh[j], acc[i][j], 0, 0, 0);
        }
    }
  }
  const int rq = (lane >> 4) * 4, cn = lane & 15;
#pragma unroll
  for (int i = 0; i < 2; i++)
#pragma unroll
    for (int r = 0; r < 4; r++) {
      const size_t rowi = (size_t)(m0 + wm + i * 16 + rq + r);
#pragma unroll
      for (int j = 0; j < 4; j++)
        C[rowi * 6144 + (n0 + wn + j * 16 + cn)] = acc[i][j][r];
    }
}

// ---------------------------------------------------------------------------
// Wo GEMM: out = ao_s(bf16, swizzled) * WoT_s. Tile 64x128, grid (32,16).
__global__ __launch_bounds__(256)
void gemm_wo2_kernel(const bf16* __restrict__ Ao, const bf16* __restrict__ WoT,
                     void* __restrict__ Cv, const ushort_t* __restrict__ msk) {
  const bool ibf = (msk[1] != 0);
  __shared__ alignas(16) bf16 sA[64 * 32];
  __shared__ alignas(16) bf16 sB[128 * 32];
  const int n0 = blockIdx.x * 128;
  const int m0 = blockIdx.y * 64;
  const int t = threadIdx.x, lane = t & 63, wave = t >> 6;
  const int wm = (wave >> 1) * 32, wn = (wave & 1) * 64;
  const int mrow = lane & 15, kq = (lane >> 4) * 8;
  const size_t aoff = (size_t)(m0 + (t >> 2)) * DM + (size_t)(t & 3) * 8;
  const size_t boff0 = (size_t)(n0 + (t >> 2)) * DM + (size_t)(t & 3) * 8;
  const size_t boff1 = (size_t)(n0 + 64 + (t >> 2)) * DM + (size_t)(t & 3) * 8;
  bf16* lA = sA + wave * 512;
  bf16* lB0 = sB + wave * 512;
  bf16* lB1 = sB + 2048 + wave * 512;

  f32x4 acc[2][4];
#pragma unroll
  for (int i = 0; i < 2; i++)
#pragma unroll
    for (int j = 0; j < 4; j++) acc[i][j] = (f32x4){0.f, 0.f, 0.f, 0.f};

  for (int kk = 0; kk < DM; kk += 32) {
    __syncthreads();
    gll16(Ao + aoff + kk, lA);
    gll16(WoT + boff0 + kk, lB0);
    gll16(WoT + boff1 + kk, lB1);
    __syncthreads();
    short8 af[2], bfr[4];
#pragma unroll
    for (int i = 0; i < 2; i++)
      af[i] = *(const short8*)&sA[aswz(wm + i * 16 + mrow, kq)];
#pragma unroll
    for (int j = 0; j < 4; j++)
      bfr[j] = *(const short8*)&sB[aswz(wn + j * 16 + mrow, kq)];
#pragma unroll
    for (int i = 0; i < 2; i++)
#pragma unroll
      for (int j = 0; j < 4; j++)
        acc[i][j] = __builtin_amdgcn_mfma_f32_16x16x32_bf16(af[i], bfr[j], acc[i][j], 0, 0, 0);
  }
  const int rq = (lane >> 4) * 4, cn = lane & 15;
#pragma unroll
  for (int i = 0; i < 2; i++)
#pragma unroll
    for (int r = 0; r < 4; r++) {
      const size_t rowi = (size_t)(m0 + wm + i * 16 + rq + r);
#pragma unroll
      for (int j = 0; j < 4; j++) {
        const size_t idx = rowi * DM + (n0 + wn + j * 16 + cn);
        if (ibf)
          ((bf16*)Cv)[idx] = __float2bfloat16(acc[i][j][r]);
        else
          ((float*)Cv)[idx] = acc[i][j][r];
      }
    }
}

// ---------------------------------------------------------------------------
// RoPE cos/sin table per (pos, d). Same double-pow expression as reference
// path -> bit-identical.
__global__ __launch_bounds__(128)
void rope_cs_kernel(float* __restrict__ cs, float* __restrict__ sn) {
  const int pos = blockIdx.x, d = threadIdx.x;
  const float inv = (float)(1.0 / pow(10000.0, (double)(d & 63) * (1.0 / 64.0)));
  const float ang = (float)pos * inv;
  cs[pos * HD + d] = cosf(ang);
  sn[pos * HD + d] = sinf(ang);
}

// RoPE for q + gq quantization. block=(128 threads)=one (h,pos).
__global__ __launch_bounds__(128)
void rope_q_gq_kernel(const float* __restrict__ qkv, const int* __restrict__ sc,
                      bf16* __restrict__ qr, float* __restrict__ gq,
                      const float* __restrict__ cs, const float* __restrict__ sn) {
  const int pos = blockIdx.x, h = blockIdx.y, d = threadIdx.x;
  __shared__ float sv[HD], sr[HD];
  __shared__ float smn, smx;
  float v = qkv[(size_t)pos * 6144 + h * HD + d];
  sv[d] = v;
  __syncthreads();
  const float c = cs[pos * HD + d], s = sn[pos * HD + d];
  float rot = (d < 64) ? -sv[d + 64] : sv[d - 64];
  float r = v * c + rot * s;
  sr[d] = r;
  qr[((size_t)h * QL + pos) * HD + d] = __float2bfloat16(r);
  __syncthreads();
  if (d == 0) {
    float mn = 3.4e38f, mx = -3.4e38f;
    for (int j = 0; j < OUTL; j++) {
      float g = sr[sc[h * HD + j]];
      mn = fminf(mn, g);
      mx = fmaxf(mx, g);
    }
    smn = mn; smx = mx;
  }
  __syncthreads();
  if (d < OUTL) {
    float g = sr[sc[h * HD + d]];
    float rng = smx - smn;
    if (rng == 0.f) rng = 1.f;
    float scale = 15.0f / rng;
    float qv = rintf((g - smn) * scale);
    qv = fminf(fmaxf(qv, 0.f), 15.f);
    gq[((size_t)h * QL + pos) * OUTL + d] = qv / scale + smn;
  }
}

// RoPE for k + gk quantization (per query-head) + v row cast.
__global__ __launch_bounds__(128)
void rope_k_gk_kernel(const float* __restrict__ qkv, const int* __restrict__ sc,
                      bf16* __restrict__ kr, bf16* __restrict__ vrow,
                      float* __restrict__ gk,
                      const float* __restrict__ cs, const float* __restrict__ sn) {
  const int pos = blockIdx.x, kvh = blockIdx.y, d = threadIdx.x;
  __shared__ float sv[HD], sr[HD];
  __shared__ float smn[GRP], smx[GRP];
  float kv = qkv[(size_t)pos * 6144 + DM + kvh * HD + d];
  float vv = qkv[(size_t)pos * 6144 + DM + NKV * HD + kvh * HD + d];
  sv[d] = kv;
  __syncthreads();
  const float c = cs[pos * HD + d], s = sn[pos * HD + d];
  float rot = (d < 64) ? -sv[d + 64] : sv[d - 64];
  float r = kv * c + rot * s;
  sr[d] = r;
  kr[((size_t)kvh * QL + pos) * HD + d] = __float2bfloat16(r);
  vrow[((size_t)kvh * QL + pos) * HD + d] = __float2bfloat16(vv);
  __syncthreads();
  if (d < 64 && (d & 15) == 0) {
    const int g = d >> 4;
    const int h = kvh * GRP + g;
    float mn = 3.4e38f, mx = -3.4e38f;
    for (int j = 0; j < OUTL; j++) {
      float x = sr[sc[h * HD + j]];
      mn = fminf(mn, x);
      mx = fmaxf(mx, x);
    }
    smn[g] = mn; smx[g] = mx;
  }
  __syncthreads();
  if (d < 64) {
    const int g = d >> 4, j = d & 15;
    const int h = kvh * GRP + g;
    float x = sr[sc[h * HD + j]];
    float rng = smx[g] - smn[g];
    if (rng == 0.f) rng = 1.f;
    float scale = 15.0f / rng;
    float qv = rintf((x - smn[g]) * scale);
    qv = fminf(fmaxf(qv, 0.f), 15.f);
    gk[((size_t)h * QL + pos) * OUTL + j] = qv / scale + smn[g];
  }
}

// ---------------------------------------------------------------------------
// Fused attention: one block = (head h, 8 queries). 256 threads = 4 waves.
__global__ __launch_bounds__(256)
void attn_kernel(const bf16* __restrict__ qr, const bf16* __restrict__ kr,
                 const bf16* __restrict__ vT, const float* __restrict__ gq,
                 const float* __restrict__ gk, bf16* __restrict__ ao) {
  const int h = blockIdx.y;
  // heavy blocks (large q0) first for better tail packing
  const int q0 = ((int)gridDim.x - 1 - (int)blockIdx.x) * 8;
  const int kvh = h >> 2;
  const int t = threadIdx.x;
  const int lane = t & 63, wave = t >> 6;
  const int mrow = lane & 15, kq = (lane >> 4) * 8;
  const int row = t >> 5, j32 = t & 31;
  const int kmax = q0 + 8;              // keys [0, kmax) are ever valid
  const bool needSel = (kmax > HC);     // else all valid keys have rank < 256

  __shared__ alignas(16) bf16 sQ[16][HD];
  __shared__ float sGq[8][OUTL];
  __shared__ alignas(16) float sBuf[8][QL];
  __shared__ float sL[8];

  {
    const int r = t >> 4, c8 = (t & 15) * 8;
    short8 z = {0, 0, 0, 0, 0, 0, 0, 0};
    if (r < 8)
      *(short8*)&sQ[r][c8] = *(const short8*)&qr[((size_t)h * QL + q0 + r) * HD + c8];
    else
      *(short8*)&sQ[r][c8] = z;
    if (needSel && t < 128)
      sGq[t >> 4][t & 15] = gq[((size_t)h * QL + q0 + (t >> 4)) * OUTL + (t & 15)];
  }
  __syncthreads();

  unsigned sel = 0xFFFFFFFFu;
  if (needSel) {
    // ---- gattn (fp32, exact path for selection), causal-bounded
    for (int kk = t; kk < kmax; kk += 256) {
      const float* gkp = &gk[((size_t)h * QL + kk) * OUTL];
      float gv[OUTL];
#pragma unroll
      for (int j = 0; j < OUTL; j++) gv[j] = gkp[j];
      const int pk = s4(kk);
#pragma unroll
      for (int r = 0; r < 8; r++) {
        float s = 0.f;
#pragma unroll
        for (int j = 0; j < OUTL; j++) s += sGq[r][j] * gv[j];
        sBuf[r][pk] = (kk <= q0 + r) ? s * 0.25f : MNEG;
      }
    }
    __syncthreads();

    // ---- exact top-256 via bit-plane radix select (stable-tie semantics)
    {
      const int base = j32 * 32;
      const int cz = j32 & 7;
      unsigned uv[32];
#pragma unroll
      for (int g = 0; g < 8; g++) {
        f32x4 v = *(const f32x4*)&sBuf[row][base + ((g ^ cz) << 2)];
#pragma unroll
        for (int m = 0; m < 4; m++) {
          const int kk = g * 4 + m;
          uv[kk] = (base + kk < kmax) ? mapf(v[m]) : 0u;
        }
      }
      // in-place 32x32 bit transpose (anti-diagonal convention)
#define TST(J, M)                                                     \
  _Pragma("unroll") for (int k2 = 0; k2 < 32; k2++) if ((k2 & (J)) == 0) { \
    unsigned tt = (uv[k2] ^ (uv[k2 + (J)] >> (J))) & (M);             \
    uv[k2] ^= tt;                                                     \
    uv[k2 + (J)] ^= (tt << (J));                                      \
  }
      TST(16, 0x0000FFFFu)
      TST(8, 0x00FF00FFu)
      TST(4, 0x0F0F0F0Fu)
      TST(2, 0x33333333u)
      TST(1, 0x55555555u)
#undef TST
      unsigned act = 0xFFFFFFFFu, gtm = 0u;
      int greater = 0, act_tot = QL;
      bool done = false;
#pragma unroll
      for (int p = 0; p < 32; p++) {
        if (__all(done)) break;
        if (!done) {
          const unsigned ones = act & uv[p];
          const int c = dppReduce32(__popc(ones));
          if (greater + c >= HC) {
            act = ones;
            act_tot = c;
          } else {
            greater += c;
            gtm |= ones;
            act ^= ones;
            act_tot -= c;
          }
          if (greater + act_tot == HC) {
            sel = __brev(gtm | act);
            done = true;
          }
        }
      }
      if (!done) {
        const unsigned gtmN = __brev(gtm), eqmN = __brev(act);
        const int needEq = HC - greater;
        const int eqc = __popc(eqmN);
        int pre = eqc;
#pragma unroll
        for (int dlt = 1; dlt < 32; dlt <<= 1) {
          int o = __shfl_up(pre, dlt, 32);
          if (j32 >= dlt) pre += o;
        }
        pre -= eqc;
        int take = needEq - pre;
        unsigned mm = eqmN;
        sel = gtmN;
        for (int i = 0; i < take && mm != 0u; i++) {
          unsigned b = mm & (0u - mm);
          sel |= b;
          mm ^= b;
        }
      }
    }
    __syncthreads();   // selection reads of sBuf done before QK overwrites
  }

  // ---- QK^T via MFMA, causal-bounded tiles
  {
    short8 aq[4];
#pragma unroll
    for (int kb = 0; kb < 4; kb++)
      aq[kb] = *(const short8*)&sQ[mrow][kb * 32 + kq];
    const bf16* krh = &kr[(size_t)kvh * QL * HD];
    const int ntmax = (kmax + 15) >> 4;
    for (int nt = wave; nt < ntmax; nt += 4) {
      const int kb0 = nt * 16;
      f32x4 acc = {0.f, 0.f, 0.f, 0.f};
#pragma unroll
      for (int kb = 0; kb < 4; kb++) {
        short8 bfr = *(const short8*)&krh[(size_t)(kb0 + mrow) * HD + kb * 32 + kq];
        acc = __builtin_amdgcn_mfma_f32_16x16x32_bf16(aq[kb], bfr, acc, 0, 0, 0);
      }
      const int key = kb0 + mrow;
      const int pk = s4(key);
#pragma unroll
      for (int r = 0; r < 4; r++) {
        const int m = (lane >> 4) * 4 + r;
        if (m < 8) {
          float v = acc[r] * 0.08838834764831845f;  // 1/sqrt(128)
          sBuf[m][pk] = (key <= q0 + m) ? v : MNEG;
        }
      }
    }
  }
  __syncthreads();

  const int kbmax = (kmax + 31) >> 5;   // PV tiles / P-overlay coverage

  // ---- masked softmax; write p as bf16 overlay at sBuf base
  {
    const int base = j32 * 32;
    const int cz = j32 & 7;
    const int rbound = q0 + row;        // keys <= rbound are valid this row
    float av[32];
#pragma unroll
    for (int g = 0; g < 8; g++) {
      f32x4 v = *(const f32x4*)&sBuf[row][base + ((g ^ cz) << 2)];
#pragma unroll
      for (int m = 0; m < 4; m++) av[g * 4 + m] = v[m];
    }
    float mx = MNEG;
#pragma unroll
    for (int kk = 0; kk < 32; kk++)
      if (((sel >> kk) & 1u) && (base + kk <= rbound)) mx = fmaxf(mx, av[kk]);
    mx = fmaxf(mx, __shfl_xor(mx, 1, 32));
    mx = fmaxf(mx, __shfl_xor(mx, 2, 32));
    mx = fmaxf(mx, __shfl_xor(mx, 4, 32));
    mx = fmaxf(mx, __shfl_xor(mx, 8, 32));
    mx = fmaxf(mx, __shfl_xor(mx, 16, 32));
    float ls = 0.f;
#pragma unroll
    for (int kk = 0; kk < 32; kk++) {
      float p = 0.f;
      if (((sel >> kk) & 1u) && (base + kk <= rbound)) {
        float e = av[kk] - mx;
        p = (e < -80.f) ? 0.f : expf(e);
        ls += p;
      }
      av[kk] = p;
    }
    ls += __shfl_xor(ls, 1, 32);
    ls += __shfl_xor(ls, 2, 32);
    ls += __shfl_xor(ls, 4, 32);
    ls += __shfl_xor(ls, 8, 32);
    ls += __shfl_xor(ls, 16, 32);
    if (j32 == 0) sL[row] = ls;
    __syncthreads();
    bf16* P = (bf16*)&sBuf[0][0];
    if (j32 < kbmax) {
      const int rk = row & 3;           // row-keyed bf16 swizzle (PV reads)
#pragma unroll
      for (int g = 0; g < 4; g++) {
        short8 pv8;
#pragma unroll
        for (int m = 0; m < 8; m++) pv8[m] = (short)f2bf(av[g * 8 + m]);
        *(short8*)&P[(size_t)row * QL + base + ((g ^ rk) << 3)] = pv8;
      }
    }
    // zero rows 8..15 of P over the PV-covered range
    {
      const int zr = 8 + row;
      if (j32 < kbmax) {
        short8 z = {0, 0, 0, 0, 0, 0, 0, 0};
#pragma unroll
        for (int i = 0; i < 4; i++)
          *(short8*)&P[(size_t)zr * QL + j32 * 32 + i * 8] = z;
      }
    }
  }
  __syncthreads();

  // ---- PV via MFMA, causal-bounded tiles (unselected p == 0)
  {
    const bf16* Pb = (const bf16*)&sBuf[0][0];
    const bf16* vTh = &vT[(size_t)kvh * HD * QL];
    const int rk = mrow & 3;
    for (int dt = wave; dt < 8; dt += 4) {
      const int d0 = dt * 16;
      f32x4 acc = {0.f, 0.f, 0.f, 0.f};
      for (int kb = 0; kb < kbmax; kb++) {
        short8 af = *(const short8*)&Pb[(size_t)mrow * QL + kb * 32 + (kq ^ (rk << 3))];
        short8 bfr = *(const short8*)&vTh[(size_t)(d0 + mrow) * QL + kb * 32 + kq];
        acc = __builtin_amdgcn_mfma_f32_16x16x32_bf16(af, bfr, acc, 0, 0, 0);
      }
#pragma unroll
      for (int r = 0; r < 4; r++) {
        const int m = (lane >> 4) * 4 + r;
        if (m < 8) {
          float outv = acc[r] / sL[m];
          // write ao in gemm_wo2's swizzled layout: chunk low2 ^= (row>>1)&3
          const int rowm = q0 + m;
          const int col = h * HD + d0 + mrow;
          const int ch = (col >> 3) ^ ((rowm >> 1) & 3);
          ao[(size_t)rowm * DM + (ch << 3) + (col & 7)] = __float2bfloat16(outv);
        }
      }
    }
  }
}

// ---------------------------------------------------------------------------
extern "C" void kernel_launch(void* const* d_in, const int* in_sizes, int n_in,
                              void* d_out, int out_size, void* d_ws, size_t ws_size,
                              hipStream_t stream) {
  (void)in_sizes; (void)n_in; (void)out_size; (void)ws_size;
  const void* hs = d_in[0];
  const ushort_t* msk = (const ushort_t*)d_in[1];  // dtype discriminator
  const void* Wq = d_in[3];
  const void* Wk = d_in[4];
  const void* Wv = d_in[5];
  const void* Wo = d_in[6];
  const int* sc = (const int*)d_in[7];

  char* ws = (char*)d_ws;
  size_t off = 0;
  auto alloc = [&](size_t bytes) {
    char* p = ws + off;
    off += (bytes + 255) & ~(size_t)255;
    return p;
  };
  float* qkv = (float*)alloc((size_t)QL * 6144 * 4);   // 25.2 MB
  bf16* ao = (bf16*)qkv;                               // aliases dead qkv
  bf16* qr = (bf16*)alloc((size_t)NH * QL * HD * 2);
  bf16* kr = (bf16*)alloc((size_t)NKV * QL * HD * 2);
  bf16* vrow = (bf16*)alloc((size_t)NKV * QL * HD * 2);
  bf16* vT = (bf16*)alloc((size_t)NKV * HD * QL * 2);
  float* gq = (float*)alloc((size_t)NH * QL * OUTL * 4);
  float* gk = (float*)alloc((size_t)NH * QL * OUTL * 4);
  float* cst = (float*)alloc((size_t)QL * HD * 4);
  float* snt = (float*)alloc((size_t)QL * HD * 4);
  bf16* Ahs = (bf16*)alloc((size_t)QL * DM * 2);       // 8.4 MB
  bf16* Als = (bf16*)alloc((size_t)QL * DM * 2);       // 8.4 MB
  bf16* WhT = (bf16*)alloc((size_t)6144 * DM * 2);     // 50.3 MB
  bf16* WlT = (bf16*)alloc((size_t)5120 * DM * 2);     // 41.9 MB
  bf16* WoT = WhT;   // aliases WhT (dead after gemm_qkv2)
  // total ~155 MB

  // 0. RoPE cos/sin tables
  rope_cs_kernel<<<dim3(QL), 128, 0, stream>>>(cst, snt);

  // 1. prepasses: split/transpose/swizzle operands to bf16
  split_a_kernel<<<dim3(2048), 256, 0, stream>>>(hs, Ahs, Als, msk);
  wsplitT_kernel<<<dim3(64, 64), 256, 0, stream>>>(Wq, 4096, WhT, WlT, 0, 1, msk);
  wsplitT_kernel<<<dim3(16, 64), 256, 0, stream>>>(Wk, 1024, WhT, WlT, 4096, 1, msk);
  wsplitT_kernel<<<dim3(16, 64), 256, 0, stream>>>(Wv, 1024, WhT, WlT, 5120, 0, msk);

  // 2. fused QKV projection (768 blocks, 3/CU)
  gemm_qkv2_kernel<<<dim3(48, 16), 256, 0, stream>>>(Ahs, Als, WhT, WlT, qkv, msk);

  // 3. RoPE + quantized-label prep
  rope_q_gq_kernel<<<dim3(QL, NH), 128, 0, stream>>>(qkv, sc, qr, gq, cst, snt);
  rope_k_gk_kernel<<<dim3(QL, NKV), 128, 0, stream>>>(qkv, sc, kr, vrow, gk, cst, snt);
  transpose_bf16_kernel<<<dim3(2, 16, NKV), 256, 0, stream>>>(
      vrow, vT, QL, HD, (long long)(QL * HD), (long long)(HD * QL));

  // 4. Wo transpose (into dead WhT space), then attention
  wsplitT_kernel<<<dim3(64, 64), 256, 0, stream>>>(Wo, 4096, WoT, WlT, 0, 0, msk);
  attn_kernel<<<dim3(QL / 8, NH), 256, 0, stream>>>(qr, kr, vT, gq, gk, ao);

  // 5. output projection (512 blocks, 2/CU; out dtype follows input dtype)
  gemm_wo2_kernel<<<dim3(32, 16), 256, 0, stream>>>(ao, WoT, d_out, msk);
}